// Round 8
// baseline (272.088 us; speedup 1.0000x reference)
//
#include <hip/hip_runtime.h>
#include <hip/hip_bf16.h>

// B=2048, N=512, D=8192.
// Pipeline (NO d_ws; scratch carved from d_out with per-block ownership):
//   1. m_norms:     mm[n]=||m_n||^2 -> p-slot (dead after rescore)
//   1b. zero_d2:    zero the 4 MB coarse-dot accumulator (head of m-region)
//   2. gemm_coarse: bf16 MFMA dot, 128x128 tiles, splitK=16 via f32 atomicAdd
//                   into d2 (grid 1024 = 4 blocks/CU at round-5 arithmetic
//                   intensity — round 7 showed occupancy gains are void if
//                   staging traffic rises with them).
//   3. rescore:     coarse argmin + margin candidates from d2; exact f32 dots
//                   only if >=2 candidates. Atomic-order noise (~1e-3) << MARGIN,
//                   so candidate set always contains the true argmin and the
//                   deterministic exact rescore fixes the output under replay.
//   4. build_lists: per-cluster ordered item lists, 4 slice copies in m-rows;
//                   counts in sd-row slice heads.
//   5. ema_scatter: grid (N,4); block (n,s) owns 2048-float slice s of cluster n;
//                   8x batched y-loads, exact-order EMA application.

#define Bb 2048
#define Nn 512
#define Dd 8192
#define MARGIN 12.0f
#define KC 16
#define KSTEPS 16   // (Dd/KC)/32

typedef __attribute__((ext_vector_type(4))) float f32x4;
typedef __attribute__((ext_vector_type(8))) short s16x8;

union Frag { unsigned u[4]; s16x8 s; };

__device__ inline unsigned pack2(float lo, float hi) {
    return __builtin_amdgcn_perm(__float_as_uint(hi), __float_as_uint(lo), 0x07060302u);
}

__device__ inline void ema4(float4& mcv, float4& scv, const float4 yv) {
#define EMA_C(c) { mcv.c = mcv.c * 0.001f + yv.c * 0.999f; \
                   float d_ = mcv.c - yv.c;                 \
                   scv.c = d_ * d_ * 0.001f + scv.c * 0.999f; }
    EMA_C(x) EMA_C(y) EMA_C(z) EMA_C(w)
#undef EMA_C
}

// ---------------- 1: m row norms ----------------
__global__ __launch_bounds__(256) void m_norms(const float* __restrict__ M,
                                               float* __restrict__ mm) {
    int n = blockIdx.x, t = threadIdx.x;
    const float4* r = (const float4*)(M + (size_t)n * Dd);
    float s = 0.f;
#pragma unroll
    for (int u = 0; u < 8; u++) {
        float4 v = r[t + 256 * u];
        s += v.x * v.x + v.y * v.y + v.z * v.z + v.w * v.w;
    }
    __shared__ float red[256];
    red[t] = s;
    __syncthreads();
    for (int off = 128; off > 0; off >>= 1) {
        if (t < off) red[t] += red[t + off];
        __syncthreads();
    }
    if (t == 0) mm[n] = red[0];
}

// ---------------- 1b: zero the d2 accumulator (1M floats) ----------------
__global__ __launch_bounds__(256) void zero_d2(float* __restrict__ d2) {
    ((float4*)d2)[blockIdx.x * 256 + threadIdx.x] = make_float4(0.f, 0.f, 0.f, 0.f);
}

// ---------------- 2: coarse bf16 MFMA GEMM, atomic splitK=16 ----------------
// grid (4 coltiles, 16 rowtiles, 16 kchunks) = 1024 blocks (4/CU), 256 threads.
// Tile 128x128, K-chunk 512 (16 steps of 32). f32 staged via global_load_lds
// with XOR seg-swizzle; converted to bf16 at fragment read.
__global__ __launch_bounds__(256) void gemm_coarse(const float* __restrict__ Y,
                                                   const float* __restrict__ M,
                                                   float* __restrict__ d2) {
    __shared__ __align__(16) float As[128 * 32];
    __shared__ __align__(16) float Bs[128 * 32];
    const int t = threadIdx.x;
    const int lane = t & 63;
    const int w = t >> 6;
    const int ct = blockIdx.x, rt = blockIdx.y, kc = blockIdx.z;

    const size_t ybase = (size_t)rt * 128 * Dd + (size_t)kc * (KSTEPS * 32);
    const size_t mbase = (size_t)ct * 128 * Dd + (size_t)kc * (KSTEPS * 32);

    int rowS[4], soff[4];
#pragma unroll
    for (int u = 0; u < 4; u++) {
        int flat = (w * 4 + u) * 64 + lane;
        int row = flat >> 3, seg = flat & 7;
        rowS[u] = row;
        soff[u] = (seg ^ (row & 7)) * 4;
    }

    const int wr0 = (w & 1) * 64, wc0 = (w >> 1) * 64;
    const int l15 = lane & 15, quad = lane >> 4;

    f32x4 acc[4][4];
#pragma unroll
    for (int i = 0; i < 4; i++)
#pragma unroll
        for (int j = 0; j < 4; j++) acc[i][j] = (f32x4)(0.0f);

    for (int step = 0; step < KSTEPS; step++) {
        const int kpos = step * 32;
#pragma unroll
        for (int u = 0; u < 4; u++) {
            const float* gA = Y + ybase + (size_t)rowS[u] * Dd + kpos + soff[u];
            const float* gB = M + mbase + (size_t)rowS[u] * Dd + kpos + soff[u];
            __builtin_amdgcn_global_load_lds(
                (const __attribute__((address_space(1))) void*)gA,
                (__attribute__((address_space(3))) void*)(As + (w * 4 + u) * 256), 16, 0, 0);
            __builtin_amdgcn_global_load_lds(
                (const __attribute__((address_space(1))) void*)gB,
                (__attribute__((address_space(3))) void*)(Bs + (w * 4 + u) * 256), 16, 0, 0);
        }
        __syncthreads();

        Frag fa[4], fb[4];
#pragma unroll
        for (int ta = 0; ta < 4; ta++) {
            int rowa = wr0 + ta * 16 + l15;
            const float* Ar = As + rowa * 32;
            int s0 = ((quad * 2) ^ (rowa & 7)) * 4;
            int s1 = ((quad * 2 + 1) ^ (rowa & 7)) * 4;
            f32x4 x0 = *(const f32x4*)(Ar + s0);
            f32x4 x1 = *(const f32x4*)(Ar + s1);
            fa[ta].u[0] = pack2(x0[0], x0[1]);
            fa[ta].u[1] = pack2(x0[2], x0[3]);
            fa[ta].u[2] = pack2(x1[0], x1[1]);
            fa[ta].u[3] = pack2(x1[2], x1[3]);
        }
#pragma unroll
        for (int tb = 0; tb < 4; tb++) {
            int rowb = wc0 + tb * 16 + l15;
            const float* Br = Bs + rowb * 32;
            int s0 = ((quad * 2) ^ (rowb & 7)) * 4;
            int s1 = ((quad * 2 + 1) ^ (rowb & 7)) * 4;
            f32x4 x0 = *(const f32x4*)(Br + s0);
            f32x4 x1 = *(const f32x4*)(Br + s1);
            fb[tb].u[0] = pack2(x0[0], x0[1]);
            fb[tb].u[1] = pack2(x0[2], x0[3]);
            fb[tb].u[2] = pack2(x1[0], x1[1]);
            fb[tb].u[3] = pack2(x1[2], x1[3]);
        }
#pragma unroll
        for (int i = 0; i < 4; i++)
#pragma unroll
            for (int j = 0; j < 4; j++)
                acc[i][j] = __builtin_amdgcn_mfma_f32_16x16x32_bf16(fa[i].s, fb[j].s, acc[i][j], 0, 0, 0);
        __syncthreads();
    }

    // atomic splitK accumulate; C/D layout: col = lane&15, row = quad*4 + reg
#pragma unroll
    for (int i = 0; i < 4; i++) {
        int rg = rt * 128 + wr0 + i * 16 + quad * 4;
#pragma unroll
        for (int j = 0; j < 4; j++) {
            int cg = ct * 128 + wc0 + j * 16 + l15;
#pragma unroll
            for (int r = 0; r < 4; r++)
                atomicAdd(&d2[(size_t)(rg + r) * Nn + cg], acc[i][j][r]);
        }
    }
}

// ---------------- 3: coarse argmin + conditional exact rescore ----------------
__global__ __launch_bounds__(256) void rescore(const float* __restrict__ Y,
                                               const float* __restrict__ M,
                                               const float* __restrict__ d2,
                                               const float* __restrict__ mm,
                                               float* __restrict__ assignF) {
    __shared__ float redW[4];
    __shared__ int candList[Nn];
    __shared__ int candCnt;
    int b = blockIdx.x, t = threadIdx.x, lane = t & 63, w = t >> 6;
    if (t == 0) candCnt = 0;

    int c0 = t, c1 = t + 256;
    float d0 = mm[c0] - 2.0f * d2[(size_t)b * Nn + c0];
    float d1 = mm[c1] - 2.0f * d2[(size_t)b * Nn + c1];

    float mn = fminf(d0, d1);
#pragma unroll
    for (int off = 32; off > 0; off >>= 1) mn = fminf(mn, __shfl_xor(mn, off));
    if (lane == 0) redW[w] = mn;
    __syncthreads();
    float thresh = fminf(fminf(redW[0], redW[1]), fminf(redW[2], redW[3])) + MARGIN;

    if (d0 <= thresh) candList[atomicAdd(&candCnt, 1)] = c0;
    if (d1 <= thresh) candList[atomicAdd(&candCnt, 1)] = c1;
    __syncthreads();
    int ncand = candCnt;

    if (ncand == 1) {                 // uncontested coarse winner: exact dot unnecessary
        if (t == 0) assignF[b] = (float)candList[0];
        return;
    }

    float bestV = 3.4e38f;
    int bestI = 0x3fffffff;
    for (int j = 0; j < ncand; j++) {
        int c = candList[j];
        const float4* yr = (const float4*)(Y + (size_t)b * Dd);
        const float4* mr = (const float4*)(M + (size_t)c * Dd);
        float p = 0.f;
#pragma unroll
        for (int u = 0; u < 8; u++) {
            float4 yv = yr[t + 256 * u];
            float4 mv = mr[t + 256 * u];
            p += yv.x * mv.x + yv.y * mv.y + yv.z * mv.z + yv.w * mv.w;
        }
#pragma unroll
        for (int off = 32; off > 0; off >>= 1) p += __shfl_xor(p, off);
        if (lane == 0) redW[w] = p;
        __syncthreads();
        if (t == 0) {
            float d2e = mm[c] - 2.0f * (redW[0] + redW[1] + redW[2] + redW[3]);
            if (d2e < bestV || (d2e == bestV && c < bestI)) { bestV = d2e; bestI = c; }
        }
        __syncthreads();
    }
    if (t == 0) assignF[b] = (float)bestI;
}

// ---------------- 4: per-cluster ordered lists, 4 slice copies ----------------
__global__ __launch_bounds__(64) void build_lists(const float* __restrict__ assignF,
                                                  float* m_out, float* sd_out) {
    int n = blockIdx.x, lane = threadIdx.x;
    int z[32];
#pragma unroll
    for (int u = 0; u < 32; u++) z[u] = (int)assignF[u * 64 + lane];
    int* lrow = (int*)(m_out + (size_t)n * Dd);
    int cnt = 0;
#pragma unroll
    for (int u = 0; u < 32; u++) {
        unsigned long long mask = __ballot(z[u] == n);
        if (z[u] == n) {
            int pos = cnt + (int)__popcll(mask & ((1ull << lane) - 1ull));
#pragma unroll
            for (int s = 0; s < 4; s++) lrow[s * 2048 + pos] = u * 64 + lane;
        }
        cnt += (int)__popcll(mask);
    }
    if (lane == 0) {
        int* crow = (int*)(sd_out + (size_t)n * Dd);
#pragma unroll
        for (int s = 0; s < 4; s++) crow[s * 2048] = cnt;
    }
}

// ---------------- 5: per-cluster sequential EMA, D-sliced x4, 8x load batch ----
__global__ __launch_bounds__(256) void ema_scatter(const float* __restrict__ Y,
                                                   const float* __restrict__ M0,
                                                   const float* __restrict__ SD0,
                                                   const float* __restrict__ P0,
                                                   float* m_out, float* sd_out, float* p_out) {
    __shared__ int lst[Bb];
    __shared__ int cntSh;
    int n = blockIdx.x, s = blockIdx.y, t = threadIdx.x;
    size_t off = (size_t)n * Dd + (size_t)s * 2048;

    if (t == 0) cntSh = ((const int*)(sd_out + off))[0];
    __syncthreads();
    int cnt = cntSh;
    const int* lsrc = (const int*)(m_out + off);
    for (int u = t; u < cnt; u += 256) lst[u] = lsrc[u];
    __syncthreads();

    float4 mc0 = *(const float4*)(M0 + off + 4 * t);
    float4 mc1 = *(const float4*)(M0 + off + 1024 + 4 * t);
    float4 sc0 = *(const float4*)(SD0 + off + 4 * t);
    float4 sc1 = *(const float4*)(SD0 + off + 1024 + 4 * t);

    // 8x batched loads (independent of the FP chain), then exact-order EMA steps.
    int j = 0;
    for (; j + 8 <= cnt; j += 8) {
        float4 y0[8], y1[8];
#pragma unroll
        for (int q = 0; q < 8; q++) {
            const float* yb = Y + (size_t)lst[j + q] * Dd + (size_t)s * 2048;
            y0[q] = *(const float4*)(yb + 4 * t);
            y1[q] = *(const float4*)(yb + 1024 + 4 * t);
        }
#pragma unroll
        for (int q = 0; q < 8; q++) { ema4(mc0, sc0, y0[q]); ema4(mc1, sc1, y1[q]); }
    }
    for (; j < cnt; j++) {
        const float* yb = Y + (size_t)lst[j] * Dd + (size_t)s * 2048;
        float4 y0 = *(const float4*)(yb + 4 * t);
        float4 y1 = *(const float4*)(yb + 1024 + 4 * t);
        ema4(mc0, sc0, y0);
        ema4(mc1, sc1, y1);
    }

    *(float4*)(m_out + off + 4 * t) = mc0;
    *(float4*)(m_out + off + 1024 + 4 * t) = mc1;
    *(float4*)(sd_out + off + 4 * t) = sc0;
    *(float4*)(sd_out + off + 1024 + 4 * t) = sc1;
    if (s == 0 && t == 0) p_out[n] = P0[n] + (float)cnt;
}

extern "C" void kernel_launch(void* const* d_in, const int* in_sizes, int n_in,
                              void* d_out, int out_size, void* d_ws, size_t ws_size,
                              hipStream_t stream) {
    const float* y  = (const float*)d_in[0];
    const float* m  = (const float*)d_in[1];
    const float* sd = (const float*)d_in[2];
    const float* p  = (const float*)d_in[3];

    float* out     = (float*)d_out;
    float* m_out   = out;                       // head doubles as d2 accumulator (4 MB)
    float* sd_out  = out + 4194304;             // rows double as count-copy slots
    float* p_out   = out + 8388608;             // also: mm norms
    float* assignF = out + 8389120;
    float* d2      = m_out;                     // 2048*512 floats, dead after rescore

    m_norms    <<<Nn, 256, 0, stream>>>(m, p_out);
    zero_d2    <<<1024, 256, 0, stream>>>(d2);
    gemm_coarse<<<dim3(4, 16, KC), 256, 0, stream>>>(y, m, d2);
    rescore    <<<Bb, 256, 0, stream>>>(y, m, d2, p_out, assignF);
    build_lists<<<Nn, 64, 0, stream>>>(assignF, m_out, sd_out);
    ema_scatter<<<dim3(Nn, 4), 256, 0, stream>>>(y, m, sd, p, m_out, sd_out, p_out);
}

// Round 9
// 228.234 us; speedup vs baseline: 1.1921x; 1.1921x over previous
//
#include <hip/hip_runtime.h>
#include <hip/hip_bf16.h>

// B=2048, N=512, D=8192.
// Pipeline (NO d_ws, NO atomics; scratch carved from d_out, per-block ownership):
//   1. m_norms:     mm[n]=||m_n||^2 -> p-slot (dead after rescore)
//   2. gemm_coarse: bf16 MFMA dot partials, 128x128 tile, splitK=8 -> m+sd (32 MB).
//                   512-THREAD blocks: 512 blocks x 8 waves = 4 waves/SIMD at
//                   round-5 staging intensity (r7: intensity loss, r8: atomic tax;
//                   this raises waves/SIMD 2->4 with both held constant).
//   3. rescore:     coarse argmin + margin candidates; exact f32 dots only if >=2
//                   candidates, CANDIDATE-PER-WAVE parallel; winner picked by
//                   index-ordered scan (deterministic under replay).
//   4. ema_scatter: grid (N,8); block (n,s) owns 1024-float slice s; wave 0
//                   ballot-scans assignF into an ordered LDS list (build_lists
//                   kernel fused away); 16x batched y-gather, exact-order EMA.

#define Bb 2048
#define Nn 512
#define Dd 8192
#define MARGIN 12.0f
#define KC 8
#define KSTEPS 32   // (Dd/KC)/32

typedef __attribute__((ext_vector_type(4))) float f32x4;
typedef __attribute__((ext_vector_type(8))) short s16x8;

union Frag { unsigned u[4]; s16x8 s; };

__device__ inline unsigned pack2(float lo, float hi) {
    return __builtin_amdgcn_perm(__float_as_uint(hi), __float_as_uint(lo), 0x07060302u);
}

__device__ inline void ema4(float4& mcv, float4& scv, const float4 yv) {
#define EMA_C(c) { mcv.c = mcv.c * 0.001f + yv.c * 0.999f; \
                   float d_ = mcv.c - yv.c;                 \
                   scv.c = d_ * d_ * 0.001f + scv.c * 0.999f; }
    EMA_C(x) EMA_C(y) EMA_C(z) EMA_C(w)
#undef EMA_C
}

// ---------------- 1: m row norms ----------------
__global__ __launch_bounds__(256) void m_norms(const float* __restrict__ M,
                                               float* __restrict__ mm) {
    int n = blockIdx.x, t = threadIdx.x;
    const float4* r = (const float4*)(M + (size_t)n * Dd);
    float s = 0.f;
#pragma unroll
    for (int u = 0; u < 8; u++) {
        float4 v = r[t + 256 * u];
        s += v.x * v.x + v.y * v.y + v.z * v.z + v.w * v.w;
    }
    __shared__ float red[256];
    red[t] = s;
    __syncthreads();
    for (int off = 128; off > 0; off >>= 1) {
        if (t < off) red[t] += red[t + off];
        __syncthreads();
    }
    if (t == 0) mm[n] = red[0];
}

// ---------------- 2: coarse bf16 MFMA GEMM (dot only), splitK=8 ----------------
// grid (4 coltiles, 16 rowtiles, 8 kchunks) = 512 blocks, 512 threads (8 waves).
// Tile 128x128, K-chunk 1024 (32 steps of 32). Wave w: rows (w&3)*32..+31,
// cols (w>>2)*64..+63. f32 staged via global_load_lds with XOR seg-swizzle;
// converted to bf16 at fragment read.
__global__ __launch_bounds__(512, 4) void gemm_coarse(const float* __restrict__ Y,
                                                      const float* __restrict__ M,
                                                      float* __restrict__ part) {
    __shared__ __align__(16) float As[128 * 32];
    __shared__ __align__(16) float Bs[128 * 32];
    const int t = threadIdx.x;
    const int lane = t & 63;
    const int w = t >> 6;
    const int ct = blockIdx.x, rt = blockIdx.y, kc = blockIdx.z;

    const size_t ybase = (size_t)rt * 128 * Dd + (size_t)kc * (KSTEPS * 32);
    const size_t mbase = (size_t)ct * 128 * Dd + (size_t)kc * (KSTEPS * 32);

    // staging map: instr u of wave w covers flat = (w*2+u)*64 + lane  (1024 slots)
    int rowS[2], soff[2];
#pragma unroll
    for (int u = 0; u < 2; u++) {
        int flat = (w * 2 + u) * 64 + lane;
        int row = flat >> 3, seg = flat & 7;
        rowS[u] = row;
        soff[u] = (seg ^ (row & 7)) * 4;
    }

    const int wr0 = (w & 3) * 32, wc0 = (w >> 2) * 64;
    const int l15 = lane & 15, quad = lane >> 4;

    f32x4 acc[2][4];
#pragma unroll
    for (int i = 0; i < 2; i++)
#pragma unroll
        for (int j = 0; j < 4; j++) acc[i][j] = (f32x4)(0.0f);

    for (int step = 0; step < KSTEPS; step++) {
        const int kpos = step * 32;
#pragma unroll
        for (int u = 0; u < 2; u++) {
            const float* gA = Y + ybase + (size_t)rowS[u] * Dd + kpos + soff[u];
            const float* gB = M + mbase + (size_t)rowS[u] * Dd + kpos + soff[u];
            __builtin_amdgcn_global_load_lds(
                (const __attribute__((address_space(1))) void*)gA,
                (__attribute__((address_space(3))) void*)(As + (w * 2 + u) * 256), 16, 0, 0);
            __builtin_amdgcn_global_load_lds(
                (const __attribute__((address_space(1))) void*)gB,
                (__attribute__((address_space(3))) void*)(Bs + (w * 2 + u) * 256), 16, 0, 0);
        }
        __syncthreads();

        Frag fa[2], fb[4];
#pragma unroll
        for (int ta = 0; ta < 2; ta++) {
            int rowa = wr0 + ta * 16 + l15;
            const float* Ar = As + rowa * 32;
            int s0 = ((quad * 2) ^ (rowa & 7)) * 4;
            int s1 = ((quad * 2 + 1) ^ (rowa & 7)) * 4;
            f32x4 x0 = *(const f32x4*)(Ar + s0);
            f32x4 x1 = *(const f32x4*)(Ar + s1);
            fa[ta].u[0] = pack2(x0[0], x0[1]);
            fa[ta].u[1] = pack2(x0[2], x0[3]);
            fa[ta].u[2] = pack2(x1[0], x1[1]);
            fa[ta].u[3] = pack2(x1[2], x1[3]);
        }
#pragma unroll
        for (int tb = 0; tb < 4; tb++) {
            int rowb = wc0 + tb * 16 + l15;
            const float* Br = Bs + rowb * 32;
            int s0 = ((quad * 2) ^ (rowb & 7)) * 4;
            int s1 = ((quad * 2 + 1) ^ (rowb & 7)) * 4;
            f32x4 x0 = *(const f32x4*)(Br + s0);
            f32x4 x1 = *(const f32x4*)(Br + s1);
            fb[tb].u[0] = pack2(x0[0], x0[1]);
            fb[tb].u[1] = pack2(x0[2], x0[3]);
            fb[tb].u[2] = pack2(x1[0], x1[1]);
            fb[tb].u[3] = pack2(x1[2], x1[3]);
        }
#pragma unroll
        for (int i = 0; i < 2; i++)
#pragma unroll
            for (int j = 0; j < 4; j++)
                acc[i][j] = __builtin_amdgcn_mfma_f32_16x16x32_bf16(fa[i].s, fb[j].s, acc[i][j], 0, 0, 0);
        __syncthreads();
    }

    // store partials; C/D layout: col = lane&15, row = quad*4 + reg
    float* P = part + (size_t)kc * (Bb * Nn);
#pragma unroll
    for (int i = 0; i < 2; i++) {
        int rg = rt * 128 + wr0 + i * 16 + quad * 4;
#pragma unroll
        for (int j = 0; j < 4; j++) {
            int cg = ct * 128 + wc0 + j * 16 + l15;
#pragma unroll
            for (int r = 0; r < 4; r++)
                P[(size_t)(rg + r) * Nn + cg] = acc[i][j][r];
        }
    }
}

// ---------------- 3: coarse argmin + wave-parallel exact rescore ----------------
__global__ __launch_bounds__(256) void rescore(const float* __restrict__ Y,
                                               const float* __restrict__ M,
                                               const float* __restrict__ part,
                                               const float* __restrict__ mm,
                                               float* __restrict__ assignF) {
    __shared__ float redW[4];
    __shared__ int candList[Nn];
    __shared__ float candD2[Nn];
    __shared__ int candCnt;
    int b = blockIdx.x, t = threadIdx.x, lane = t & 63, w = t >> 6;
    if (t == 0) candCnt = 0;

    int c0 = t, c1 = t + 256;
    float dot0 = 0.f, dot1 = 0.f;
#pragma unroll
    for (int k = 0; k < KC; k++) {
        dot0 += part[(size_t)k * (Bb * Nn) + (size_t)b * Nn + c0];
        dot1 += part[(size_t)k * (Bb * Nn) + (size_t)b * Nn + c1];
    }
    float d0 = mm[c0] - 2.0f * dot0;
    float d1 = mm[c1] - 2.0f * dot1;

    float mn = fminf(d0, d1);
#pragma unroll
    for (int off = 32; off > 0; off >>= 1) mn = fminf(mn, __shfl_xor(mn, off));
    if (lane == 0) redW[w] = mn;
    __syncthreads();
    float thresh = fminf(fminf(redW[0], redW[1]), fminf(redW[2], redW[3])) + MARGIN;

    if (d0 <= thresh) candList[atomicAdd(&candCnt, 1)] = c0;
    if (d1 <= thresh) candList[atomicAdd(&candCnt, 1)] = c1;
    __syncthreads();
    int ncand = candCnt;

    if (ncand == 1) {                 // uncontested coarse winner: exact dot unnecessary
        if (t == 0) assignF[b] = (float)candList[0];
        return;
    }

    // each wave handles candidates j = w, w+4, ... (full-row dot per wave)
    const float4* yr = (const float4*)(Y + (size_t)b * Dd);
    for (int j = w; j < ncand; j += 4) {
        int c = candList[j];
        const float4* mr = (const float4*)(M + (size_t)c * Dd);
        float p = 0.f;
#pragma unroll 8
        for (int u = 0; u < 32; u++) {
            float4 yv = yr[u * 64 + lane];
            float4 mv = mr[u * 64 + lane];
            p += yv.x * mv.x + yv.y * mv.y + yv.z * mv.z + yv.w * mv.w;
        }
#pragma unroll
        for (int off = 32; off > 0; off >>= 1) p += __shfl_xor(p, off);
        if (lane == 0) candD2[j] = mm[c] - 2.0f * p;
    }
    __syncthreads();

    if (t == 0) {       // index-ordered scan: deterministic regardless of list order
        float bestV = 3.4e38f;
        int bestI = 0x3fffffff;
        for (int j = 0; j < ncand; j++) {
            float d2e = candD2[j];
            int c = candList[j];
            if (d2e < bestV || (d2e == bestV && c < bestI)) { bestV = d2e; bestI = c; }
        }
        assignF[b] = (float)bestI;
    }
}

// ---------------- 4: per-cluster sequential EMA, D-sliced x8, fused list build ----
__global__ __launch_bounds__(256) void ema_scatter(const float* __restrict__ Y,
                                                   const float* __restrict__ M0,
                                                   const float* __restrict__ SD0,
                                                   const float* __restrict__ P0,
                                                   const float* __restrict__ assignF,
                                                   float* __restrict__ m_out,
                                                   float* __restrict__ sd_out,
                                                   float* __restrict__ p_out) {
    __shared__ int lst[Bb];
    __shared__ int cntSh;
    int n = blockIdx.x, s = blockIdx.y, t = threadIdx.x, lane = t & 63, w = t >> 6;

    if (w == 0) {       // wave 0 ballot-scans the assignments into an ordered list
        int cnt = 0;
#pragma unroll
        for (int u = 0; u < 32; u++) {
            int zi = (int)assignF[u * 64 + lane];
            unsigned long long mask = __ballot(zi == n);
            if (zi == n) lst[cnt + (int)__popcll(mask & ((1ull << lane) - 1ull))] = u * 64 + lane;
            cnt += (int)__popcll(mask);
        }
        if (lane == 0) {
            cntSh = cnt;
            if (s == 0) p_out[n] = P0[n] + (float)cnt;
        }
    }
    __syncthreads();
    int cnt = cntSh;

    size_t off = (size_t)n * Dd + (size_t)s * 1024;
    float4 mc = *(const float4*)(M0 + off + 4 * t);
    float4 sc = *(const float4*)(SD0 + off + 4 * t);

    int j = 0;
    for (; j + 16 <= cnt; j += 16) {     // 16x batched gathers, exact-order EMA
        float4 yv[16];
#pragma unroll
        for (int q = 0; q < 16; q++)
            yv[q] = *(const float4*)(Y + (size_t)lst[j + q] * Dd + (size_t)s * 1024 + 4 * t);
#pragma unroll
        for (int q = 0; q < 16; q++) ema4(mc, sc, yv[q]);
    }
    for (; j < cnt; j++) {
        float4 yv = *(const float4*)(Y + (size_t)lst[j] * Dd + (size_t)s * 1024 + 4 * t);
        ema4(mc, sc, yv);
    }

    *(float4*)(m_out + off + 4 * t) = mc;
    *(float4*)(sd_out + off + 4 * t) = sc;
}

extern "C" void kernel_launch(void* const* d_in, const int* in_sizes, int n_in,
                              void* d_out, int out_size, void* d_ws, size_t ws_size,
                              hipStream_t stream) {
    const float* y  = (const float*)d_in[0];
    const float* m  = (const float*)d_in[1];
    const float* sd = (const float*)d_in[2];
    const float* p  = (const float*)d_in[3];

    float* out     = (float*)d_out;
    float* m_out   = out;                       // partials k=0..3 live here pre-rescore
    float* sd_out  = out + 4194304;             // partials k=4..7 live here pre-rescore
    float* p_out   = out + 8388608;             // also: mm norms (dead after rescore)
    float* assignF = out + 8389120;
    float* part    = out;                       // 8 x 1M floats = m+sd regions exactly

    m_norms    <<<Nn, 256, 0, stream>>>(m, p_out);
    gemm_coarse<<<dim3(4, 16, KC), 512, 0, stream>>>(y, m, part);
    rescore    <<<Bb, 256, 0, stream>>>(y, m, part, p_out, assignF);
    ema_scatter<<<dim3(Nn, 8), 256, 0, stream>>>(y, m, sd, p, assignF, m_out, sd_out, p_out);
}